// Round 13
// baseline (3249.951 us; speedup 1.0000x reference)
//
#include <hip/hip_runtime.h>
#include <hip/hip_bf16.h>
#include <stdint.h>

typedef unsigned short u16;
typedef __attribute__((ext_vector_type(8))) short bf16x8;
typedef __attribute__((ext_vector_type(4))) float f32x4;

#define KD 4096   // in_features (K)
#define ND 4096   // out_features (N)
#define MD 8192   // rows of x
#define NKT2 128  // K-tiles of BK=32

// ---- fp32 -> bf16 round-to-nearest-even ----
__device__ __forceinline__ u16 f2bf(float f) {
    uint32_t u = __float_as_uint(f);
    u += 0x7FFFu + ((u >> 16) & 1u);
    return (u16)(u >> 16);
}

// ---- async global->LDS 16B ----
__device__ __forceinline__ void gload_lds16(const u16* g, u16* l) {
    __builtin_amdgcn_global_load_lds(
        (const __attribute__((address_space(1))) void*)g,
        (__attribute__((address_space(3))) void*)l, 16, 0, 0);
}

// =====================================================================
// Kernel 1 (merged prep): blocks [0,2048) build W_t, blocks [2048,18432)
// convert x fp32->bf16.
// =====================================================================
__global__ __launch_bounds__(256) void prep(
    const int* __restrict__ index, const float4* __restrict__ cluster4,
    u16* __restrict__ wt,
    const float4* __restrict__ x4, uint4* __restrict__ xb) {
    __shared__ int idx_s[64][32];
    const int bid = blockIdx.x;
    const int t   = threadIdx.x;
    if (bid < 2048) {
        const int k0 = (bid & 63) * 64;
        const int g0 = (bid >> 6) * 32;
        #pragma unroll
        for (int r = 0; r < 8; ++r) {
            int k = (t >> 5) + r * 8;
            int g = t & 31;
            idx_s[k][g] = index[(size_t)(k0 + k) * 1024 + g0 + g];
        }
        __syncthreads();
        const int g_local = t >> 3;
        const int k_local = (t & 7) * 8;
        u16 pk[4][8];
        #pragma unroll
        for (int j = 0; j < 8; ++j) {
            int idx = idx_s[k_local + j][g_local];
            float4 v = cluster4[idx];
            pk[0][j] = f2bf(v.x);
            pk[1][j] = f2bf(v.y);
            pk[2][j] = f2bf(v.z);
            pk[3][j] = f2bf(v.w);
        }
        const size_t nbase = (size_t)g0 * 4 + g_local * 4;
        #pragma unroll
        for (int c = 0; c < 4; ++c) {
            *reinterpret_cast<uint4*>(wt + (nbase + c) * KD + k0 + k_local) =
                *reinterpret_cast<const uint4*>(pk[c]);
        }
    } else {
        int i = (bid - 2048) * 256 + t;
        float4 a = x4[2 * i];
        float4 b = x4[2 * i + 1];
        u16 r[8] = {f2bf(a.x), f2bf(a.y), f2bf(a.z), f2bf(a.w),
                    f2bf(b.x), f2bf(b.y), f2bf(b.z), f2bf(b.w)};
        xb[i] = *reinterpret_cast<const uint4*>(r);
    }
}

// =====================================================================
// Kernel 2: 256x256 tile, BK=32, 8-phase GEMM, 16x16x32 MFMA.
// Round-10 schedule verbatim with halved K-step so LDS = 64 KiB ->
// 2 blocks/CU (16 waves/CU): cross-block overlap fills the ~48% idle
// MFMA slots (m114 mechanism). __launch_bounds__(512,4) pins <=128
// VGPR (2-block requirement).
// LDS layout per buf (16384 u16): A [256 rows][32 elems] then B same.
// 64-B rows = 4x16B slots; swizzle slot' = khi ^ ((row>>1)&3)
// (2 lanes/bank-window = free). Same involution on gload source
// (scol) and ds_read (ce); (row>>1)&3 is frow-invariant (+16k rows).
// vmcnt queue (1 load/STAGE, in-order; entry invariant [B0',A0']):
//  P4 WVM(2): drains B0',A0',A1',B1' = all buf1 -> BAR. P8 WVM(2):
//  drains B0,A0,A1,B1 = all buf0(tp2) -> BAR; invariant restored.
// Round-11 lesson preserved: B0 staged at P3/P7 (earliest legal),
// A0 at P4/P8; stage order unchanged from round-10.
// =====================================================================
__global__ __launch_bounds__(512, 4) void gemm256(
    const u16* __restrict__ A,    // [MD][KD] bf16
    const u16* __restrict__ Bt,   // [ND][KD] bf16
    const float* __restrict__ bias,
    float* __restrict__ C) {
    __shared__ __align__(16) u16 lds[32768];   // 64 KiB

    const int t    = threadIdx.x;
    const int lane = t & 63;
    const int wave = t >> 6;
    const int wm   = wave >> 2;      // 0..1
    const int wn   = wave & 3;       // 0..3

    // T1: bijective XCD swizzle (512 % 8 == 0)
    const int bid = blockIdx.x;
    const int swz = (bid & 7) * 64 + (bid >> 3);
    const int n0  = (swz & 15) * 256;
    const int m0  = (swz >> 4) * 256;

    // staging: thread t -> physical (row=t>>2, slot=t&3) in a
    // [128 rows][64 B] half-tile; global source col inverse-swizzled.
    const int srow = t >> 2;
    const int scol = ((t & 3) ^ ((t >> 3) & 3)) * 8;   // elems
    const u16* srcA = A  + (size_t)(m0 + srow) * KD + scol;
    const u16* srcB = Bt + (size_t)(n0 + srow) * KD + scol;
    const size_t HS = (size_t)128 * KD;   // half-tile (h=1) row step

    // fragment-read swizzled column offset (elems): khi ^ ((frow>>1)&3)
    const int frow = lane & 15;
    const int ce   = (((lane >> 4) ^ ((frow >> 1) & 3))) * 8;

    f32x4 acc[8][4] = {};
    bf16x8 aS[2][4];      // [mh][f]
    bf16x8 bR[2];         // [g] (one nh at a time)

#define STAGE(isB, b, h, kt)                                               \
    gload_lds16(((isB) ? srcB : srcA) + (size_t)(h) * HS + (kt) * 32,      \
                (u16*)lds + (b) * 16384 + (isB) * 8192 + (h) * 4096 + t * 8)

#define READA(b, mh) do {                                                  \
    _Pragma("unroll") for (int f_ = 0; f_ < 4; ++f_)                       \
        aS[mh][f_] = *(const bf16x8*)((u16*)lds + (b) * 16384 +            \
            ((wm * 128 + (mh) * 64 + f_ * 16 + frow) * 32) + ce);          \
    } while (0)

#define READB(b, nh) do {                                                  \
    _Pragma("unroll") for (int g_ = 0; g_ < 2; ++g_)                       \
        bR[g_] = *(const bf16x8*)((u16*)lds + (b) * 16384 + 8192 +         \
            ((wn * 64 + (nh) * 32 + g_ * 16 + frow) * 32) + ce);           \
    } while (0)

#define MFMA8(mh, nh) do {                                                 \
    _Pragma("unroll") for (int f_ = 0; f_ < 4; ++f_)                       \
    _Pragma("unroll") for (int g_ = 0; g_ < 2; ++g_)                       \
        acc[(mh)*4+f_][(nh)*2+g_] = __builtin_amdgcn_mfma_f32_16x16x32_bf16( \
            aS[mh][f_], bR[g_], acc[(mh)*4+f_][(nh)*2+g_], 0, 0, 0);       \
    } while (0)

#define BAR() __builtin_amdgcn_s_barrier()
#define WAIT_LGKM() do { asm volatile("s_waitcnt lgkmcnt(0)" ::: "memory"); \
                         __builtin_amdgcn_sched_barrier(0); } while (0)
#define HINT_LGKM2() asm volatile("s_waitcnt lgkmcnt(2)" ::: "memory")
#define WAIT_VM2() asm volatile("s_waitcnt vmcnt(2)" ::: "memory")
#define PRIO1() __builtin_amdgcn_s_setprio(1)
#define PRIO0() __builtin_amdgcn_s_setprio(0)

    // ---- prologue: tile0 (buf0) fully + tile1.B0 + tile1.A0 ----
    STAGE(0, 0, 0, 0);   // buf0.A0  <- tile0
    STAGE(0, 0, 1, 0);   // buf0.A1
    STAGE(1, 0, 0, 0);   // buf0.B0
    STAGE(1, 0, 1, 0);   // buf0.B1
    STAGE(1, 1, 0, 1);   // buf1.B0  <- tile1
    STAGE(0, 1, 0, 1);   // buf1.A0
    WAIT_VM2();          // own tile0 stripes landed; barrier = all waves
    BAR();

    // ---- main loop: 2 K-tiles / iteration, 8 phases ----
    for (int I = 0; I < NKT2 / 2; ++I) {
        const int tb  = 2 * I + 1;
        const int tp2 = (2 * I + 2) & (NKT2 - 1);  // wraps harmlessly at end
        const int tp3 = (2 * I + 3) & (NKT2 - 1);

        // P1: q(0,0) buf0; stage buf1.A1 (tb); pre-issue P2's A-frags
        READA(0, 0); READB(0, 0); STAGE(0, 1, 1, tb);
        HINT_LGKM2();
        BAR(); WAIT_LGKM();
        PRIO1(); MFMA8(0, 0); PRIO0();
        READA(0, 1);
        BAR();
        // P2: q(1,0) buf0; stage buf1.B1 (tb); pre-issue P3's B-frags
        STAGE(1, 1, 1, tb);
        BAR(); WAIT_LGKM();
        PRIO1(); MFMA8(1, 0); PRIO0();
        READB(0, 1);
        BAR();
        // P3: q(0,1) buf0; stage buf0.B0 (tp2)
        STAGE(1, 0, 0, tp2);
        BAR(); WAIT_LGKM();
        PRIO1(); MFMA8(0, 1); PRIO0();
        BAR();
        // P4: q(1,1) buf0; stage buf0.A0 (tp2); vmcnt AFTER MFMA
        STAGE(0, 0, 0, tp2);
        BAR(); WAIT_LGKM();
        PRIO1(); MFMA8(1, 1); PRIO0();
        WAIT_VM2();      // buf1 (tb) landed; BAR => for ALL waves
        BAR();
        // P5: q(0,0) buf1; stage buf0.A1 (tp2); pre-issue P6's A-frags
        READA(1, 0); READB(1, 0); STAGE(0, 0, 1, tp2);
        HINT_LGKM2();
        BAR(); WAIT_LGKM();
        PRIO1(); MFMA8(0, 0); PRIO0();
        READA(1, 1);
        BAR();
        // P6: q(1,0) buf1; stage buf0.B1 (tp2); pre-issue P7's B-frags
        STAGE(1, 0, 1, tp2);
        BAR(); WAIT_LGKM();
        PRIO1(); MFMA8(1, 0); PRIO0();
        READB(1, 1);
        BAR();
        // P7: q(0,1) buf1; stage buf1.B0 (tp3)
        STAGE(1, 1, 0, tp3);
        BAR(); WAIT_LGKM();
        PRIO1(); MFMA8(0, 1); PRIO0();
        BAR();
        // P8: q(1,1) buf1; stage buf1.A0 (tp3); vmcnt AFTER MFMA
        STAGE(0, 1, 0, tp3);
        BAR(); WAIT_LGKM();
        PRIO1(); MFMA8(1, 1); PRIO0();
        WAIT_VM2();      // buf0 (tp2) landed; BAR => for ALL waves
        BAR();
    }

    // ---- epilogue: C = acc + bias (16x16 C/D map, m89-verified) ----
    const int crow = (lane >> 4) * 4;
    float bv[4];
    #pragma unroll
    for (int g = 0; g < 4; ++g)
        bv[g] = bias[n0 + wn * 64 + g * 16 + frow];
    #pragma unroll
    for (int f = 0; f < 8; ++f) {
        const int mrow = m0 + wm * 128 + f * 16 + crow;
        #pragma unroll
        for (int g = 0; g < 4; ++g) {
            float* cp = C + (size_t)mrow * ND + n0 + wn * 64 + g * 16 + frow;
            #pragma unroll
            for (int r = 0; r < 4; ++r)
                cp[(size_t)r * ND] = acc[f][g][r] + bv[g];
        }
    }
#undef STAGE
#undef READA
#undef READB
#undef MFMA8
#undef BAR
#undef WAIT_LGKM
#undef HINT_LGKM2
#undef WAIT_VM2
}

// =====================================================================
// Fallback (workspace too small): fp32 inline gather
// =====================================================================
__global__ __launch_bounds__(256) void fallback_gemm(
    const float* __restrict__ x, const float4* __restrict__ cluster4,
    const int* __restrict__ index, const float* __restrict__ bias,
    float* __restrict__ out) {
    const int m = blockIdx.y;
    const int g = blockIdx.x * 256 + threadIdx.x;
    const float* xr = x + (size_t)m * KD;
    float a0 = 0.f, a1 = 0.f, a2 = 0.f, a3 = 0.f;
    for (int k = 0; k < KD; ++k) {
        float xv = xr[k];
        float4 cv = cluster4[index[(size_t)k * 1024 + g]];
        a0 += xv * cv.x; a1 += xv * cv.y; a2 += xv * cv.z; a3 += xv * cv.w;
    }
    size_t o = (size_t)m * ND + (size_t)g * 4;
    out[o + 0] = a0 + bias[g * 4 + 0];
    out[o + 1] = a1 + bias[g * 4 + 1];
    out[o + 2] = a2 + bias[g * 4 + 2];
    out[o + 3] = a3 + bias[g * 4 + 3];
}

extern "C" void kernel_launch(void* const* d_in, const int* in_sizes, int n_in,
                              void* d_out, int out_size, void* d_ws, size_t ws_size,
                              hipStream_t stream) {
    const float* x       = (const float*)d_in[0];
    const float* cluster = (const float*)d_in[1];
    const int*   index   = (const int*)d_in[2];
    const float* bias    = (const float*)d_in[3];
    float* out = (float*)d_out;

    const size_t WT_BYTES = (size_t)ND * KD * sizeof(u16);
    const size_t XB_BYTES = (size_t)MD * KD * sizeof(u16);

    if (ws_size >= WT_BYTES + XB_BYTES) {
        u16* wt = (u16*)d_ws;
        u16* xb = (u16*)((char*)d_ws + WT_BYTES);
        prep<<<2048 + (MD * KD / 8) / 256, 256, 0, stream>>>(
            index, (const float4*)cluster, wt, (const float4*)x, (uint4*)xb);
        gemm256<<<dim3((MD / 256) * (ND / 256)), 512, 0, stream>>>(
            xb, wt, bias, out);
    } else {
        fallback_gemm<<<dim3(1024 / 256, MD), 256, 0, stream>>>(
            x, (const float4*)cluster, index, bias, out);
    }
}

// Round 14
// 272.143 us; speedup vs baseline: 11.9421x; 11.9421x over previous
//
#include <hip/hip_runtime.h>
#include <hip/hip_bf16.h>
#include <stdint.h>

typedef unsigned short u16;
typedef __attribute__((ext_vector_type(8))) short bf16x8;
typedef __attribute__((ext_vector_type(4))) float f32x4;

#define KD 4096   // in_features (K)
#define ND 4096   // out_features (N)
#define MD 8192   // rows of x
#define NKT 64    // K-tiles of BK=64

// ---- fp32 -> bf16 round-to-nearest-even ----
__device__ __forceinline__ u16 f2bf(float f) {
    uint32_t u = __float_as_uint(f);
    u += 0x7FFFu + ((u >> 16) & 1u);
    return (u16)(u >> 16);
}

// ---- async global->LDS 16B ----
__device__ __forceinline__ void gload_lds16(const u16* g, u16* l) {
    __builtin_amdgcn_global_load_lds(
        (const __attribute__((address_space(1))) void*)g,
        (__attribute__((address_space(3))) void*)l, 16, 0, 0);
}

// =====================================================================
// Kernel 1 (merged prep): blocks [0,2048) build W_t, blocks [2048,18432)
// convert x fp32->bf16. Overlaps the latency-bound cluster gather with
// the BW-bound convert; saves one launch gap.
// =====================================================================
__global__ __launch_bounds__(256) void prep(
    const int* __restrict__ index, const float4* __restrict__ cluster4,
    u16* __restrict__ wt,
    const float4* __restrict__ x4, uint4* __restrict__ xb) {
    __shared__ int idx_s[64][32];
    const int bid = blockIdx.x;
    const int t   = threadIdx.x;
    if (bid < 2048) {
        // ---- build W_t: W_t[n][k] = cluster[index[k*1024 + n/4]][n&3] ----
        const int k0 = (bid & 63) * 64;
        const int g0 = (bid >> 6) * 32;
        #pragma unroll
        for (int r = 0; r < 8; ++r) {
            int k = (t >> 5) + r * 8;
            int g = t & 31;
            idx_s[k][g] = index[(size_t)(k0 + k) * 1024 + g0 + g];
        }
        __syncthreads();
        const int g_local = t >> 3;
        const int k_local = (t & 7) * 8;
        u16 pk[4][8];
        #pragma unroll
        for (int j = 0; j < 8; ++j) {
            int idx = idx_s[k_local + j][g_local];
            float4 v = cluster4[idx];
            pk[0][j] = f2bf(v.x);
            pk[1][j] = f2bf(v.y);
            pk[2][j] = f2bf(v.z);
            pk[3][j] = f2bf(v.w);
        }
        const size_t nbase = (size_t)g0 * 4 + g_local * 4;
        #pragma unroll
        for (int c = 0; c < 4; ++c) {
            *reinterpret_cast<uint4*>(wt + (nbase + c) * KD + k0 + k_local) =
                *reinterpret_cast<const uint4*>(pk[c]);
        }
    } else {
        // ---- cvt x: 8 fp32 -> 8 bf16 per thread ----
        int i = (bid - 2048) * 256 + t;
        float4 a = x4[2 * i];
        float4 b = x4[2 * i + 1];
        u16 r[8] = {f2bf(a.x), f2bf(a.y), f2bf(a.z), f2bf(a.w),
                    f2bf(b.x), f2bf(b.y), f2bf(b.z), f2bf(b.w)};
        xb[i] = *reinterpret_cast<const uint4*>(r);
    }
}

// =====================================================================
// Kernel 2: 256x256x64 8-phase GEMM, 16x16x32 MFMA — round-10 verified
// artifact (235 us, MfmaUtil 51.5, conflicts 0, VGPR 128).
// Session constraints discovered (do not violate):
//  - B0 (rows 0-127) is read by wn∈{0,1} waves at BOTH nh quadrants;
//    the READB(0,1) pre-issued at end-P2 still reads B0 -> B0 may not
//    be re-staged before P3 (buf1.B0 before P7). (round-11 race)
//  - vmcnt is per-wave; cross-wave landing guarantee is WVM -> BAR.
//    (round-4 race)
//  - 256x256 tile => acc alone = 128 VGPR => 1 block/CU is forced;
//    launch_bounds beyond (512,2) spills acc to scratch. (round-13)
//  - 32x32x16 MFMA's 32-lane column read defeats the (row&7) XOR
//    swizzle -> 4-way conflicts. (round-3)
// =====================================================================
__global__ __launch_bounds__(512, 2) void gemm256(
    const u16* __restrict__ A,    // [MD][KD] bf16
    const u16* __restrict__ Bt,   // [ND][KD] bf16
    const float* __restrict__ bias,
    float* __restrict__ C) {
    __shared__ __align__(16) u16 lds[65536];   // 128 KiB

    const int t    = threadIdx.x;
    const int lane = t & 63;
    const int wave = t >> 6;
    const int wm   = wave >> 2;      // 0..1
    const int wn   = wave & 3;       // 0..3

    // T1: bijective XCD swizzle (512 % 8 == 0)
    const int bid = blockIdx.x;
    const int swz = (bid & 7) * 64 + (bid >> 3);
    const int n0  = (swz & 15) * 256;
    const int m0  = (swz >> 4) * 256;

    // staging: physical p = i*8192 + t*16 bytes within a 16 KiB half-tile
    // region [128 rows][128 B]; source address inverse-swizzled.
    const u16* srcA[2]; const u16* srcB[2];
    #pragma unroll
    for (int i = 0; i < 2; ++i) {
        int p   = i * 8192 + t * 16;
        int row = p >> 7;
        int cb  = (p & 127) ^ ((row & 7) << 4);
        srcA[i] = A  + (size_t)(m0 + row) * KD + (cb >> 1);
        srcB[i] = Bt + (size_t)(n0 + row) * KD + (cb >> 1);
    }
    const size_t HS = (size_t)128 * KD;   // half-tile (h=1) row step

    // fragment-read swizzled column offsets (u16 elems), per kstep
    const int frow = lane & 15;
    int ce2[2];
    #pragma unroll
    for (int s = 0; s < 2; ++s)
        ce2[s] = ((s * 64 + ((lane >> 4) * 16)) ^ ((lane & 7) << 4)) >> 1;

    f32x4 acc[8][4] = {};
    bf16x8 aS[2][4][2];   // [mh][f][kstep]
    bf16x8 bR[2][2];      // [g][kstep] (one nh at a time)

#define STAGE(isB, b, h, kt) do {                                          \
    _Pragma("unroll")                                                      \
    for (int i_ = 0; i_ < 2; ++i_) {                                       \
        const u16* s_ = ((isB) ? srcB[i_] : srcA[i_])                      \
                        + (size_t)(h) * HS + (kt) * 64;                    \
        u16* d_ = (u16*)lds + (b) * 32768 + (isB) * 16384                  \
                  + (h) * 8192 + i_ * 4096 + t * 8;                        \
        gload_lds16(s_, d_);                                               \
    } } while (0)

#define READA(b, mh) do {                                                  \
    _Pragma("unroll") for (int f_ = 0; f_ < 4; ++f_)                       \
    _Pragma("unroll") for (int s_ = 0; s_ < 2; ++s_)                       \
        aS[mh][f_][s_] = *(const bf16x8*)((u16*)lds + (b) * 32768 +        \
            ((wm * 128 + (mh) * 64 + f_ * 16 + frow) * 64) + ce2[s_]);     \
    } while (0)

#define READB(b, nh) do {                                                  \
    _Pragma("unroll") for (int g_ = 0; g_ < 2; ++g_)                       \
    _Pragma("unroll") for (int s_ = 0; s_ < 2; ++s_)                       \
        bR[g_][s_] = *(const bf16x8*)((u16*)lds + (b) * 32768 + 16384 +    \
            ((wn * 64 + (nh) * 32 + g_ * 16 + frow) * 64) + ce2[s_]);      \
    } while (0)

#define MFMA16(mh, nh) do {                                                \
    _Pragma("unroll") for (int f_ = 0; f_ < 4; ++f_)                       \
    _Pragma("unroll") for (int g_ = 0; g_ < 2; ++g_)                       \
    _Pragma("unroll") for (int s_ = 0; s_ < 2; ++s_)                       \
        acc[(mh)*4+f_][(nh)*2+g_] = __builtin_amdgcn_mfma_f32_16x16x32_bf16( \
            aS[mh][f_][s_], bR[g_][s_], acc[(mh)*4+f_][(nh)*2+g_], 0,0,0); \
    } while (0)

#define BAR() __builtin_amdgcn_s_barrier()
#define WAIT_LGKM() do { asm volatile("s_waitcnt lgkmcnt(0)" ::: "memory"); \
                         __builtin_amdgcn_sched_barrier(0); } while (0)
#define HINT_LGKM8() asm volatile("s_waitcnt lgkmcnt(8)" ::: "memory")
#define WAIT_VM4() asm volatile("s_waitcnt vmcnt(4)" ::: "memory")
#define PRIO1() __builtin_amdgcn_s_setprio(1)
#define PRIO0() __builtin_amdgcn_s_setprio(0)

    // ---- prologue: tile0 (buf0) fully + tile1.B0 + tile1.A0 ----
    STAGE(0, 0, 0, 0);   // buf0.A0  <- tile0
    STAGE(0, 0, 1, 0);   // buf0.A1
    STAGE(1, 0, 0, 0);   // buf0.B0
    STAGE(1, 0, 1, 0);   // buf0.B1
    STAGE(1, 1, 0, 1);   // buf1.B0  <- tile1
    STAGE(0, 1, 0, 1);   // buf1.A0
    WAIT_VM4();          // own tile0 stripes landed; barrier = all waves
    BAR();

    // ---- main loop: 2 K-tiles / iteration, 8 phases ----
    for (int I = 0; I < NKT / 2; ++I) {
        const int tb  = 2 * I + 1;
        const int tp2 = (2 * I + 2) & (NKT - 1);   // wraps harmlessly at end
        const int tp3 = (2 * I + 3) & (NKT - 1);

        // P1: q(0,0) buf0; stage buf1.A1 (tb); pre-issue P2's A-frags
        READA(0, 0); READB(0, 0); STAGE(0, 1, 1, tb);
        HINT_LGKM8();
        BAR(); WAIT_LGKM();
        PRIO1(); MFMA16(0, 0); PRIO0();
        READA(0, 1);
        BAR();
        // P2: q(1,0) buf0; stage buf1.B1 (tb); pre-issue P3's B-frags
        STAGE(1, 1, 1, tb);
        BAR(); WAIT_LGKM();
        PRIO1(); MFMA16(1, 0); PRIO0();
        READB(0, 1);
        BAR();
        // P3: q(0,1) buf0; stage buf0.B0 (tp2)
        STAGE(1, 0, 0, tp2);
        BAR(); WAIT_LGKM();
        PRIO1(); MFMA16(0, 1); PRIO0();
        BAR();
        // P4: q(1,1) buf0; stage buf0.A0 (tp2); vmcnt AFTER MFMA
        STAGE(0, 0, 0, tp2);
        BAR(); WAIT_LGKM();
        PRIO1(); MFMA16(1, 1); PRIO0();
        WAIT_VM4();      // buf1 (tb) landed; BAR => for ALL waves
        BAR();
        // P5: q(0,0) buf1; stage buf0.A1 (tp2); pre-issue P6's A-frags
        READA(1, 0); READB(1, 0); STAGE(0, 0, 1, tp2);
        HINT_LGKM8();
        BAR(); WAIT_LGKM();
        PRIO1(); MFMA16(0, 0); PRIO0();
        READA(1, 1);
        BAR();
        // P6: q(1,0) buf1; stage buf0.B1 (tp2); pre-issue P7's B-frags
        STAGE(1, 0, 1, tp2);
        BAR(); WAIT_LGKM();
        PRIO1(); MFMA16(1, 0); PRIO0();
        READB(1, 1);
        BAR();
        // P7: q(0,1) buf1; stage buf1.B0 (tp3)
        STAGE(1, 1, 0, tp3);
        BAR(); WAIT_LGKM();
        PRIO1(); MFMA16(0, 1); PRIO0();
        BAR();
        // P8: q(1,1) buf1; stage buf1.A0 (tp3); vmcnt AFTER MFMA
        STAGE(0, 1, 0, tp3);
        BAR(); WAIT_LGKM();
        PRIO1(); MFMA16(1, 1); PRIO0();
        WAIT_VM4();      // buf0 (tp2) landed; BAR => for ALL waves
        BAR();
    }

    // ---- epilogue: C = acc + bias (16x16 C/D map, m89-verified) ----
    const int crow = (lane >> 4) * 4;
    float bv[4];
    #pragma unroll
    for (int g = 0; g < 4; ++g)
        bv[g] = bias[n0 + wn * 64 + g * 16 + frow];
    #pragma unroll
    for (int f = 0; f < 8; ++f) {
        const int mrow = m0 + wm * 128 + f * 16 + crow;
        #pragma unroll
        for (int g = 0; g < 4; ++g) {
            float* cp = C + (size_t)mrow * ND + n0 + wn * 64 + g * 16 + frow;
            #pragma unroll
            for (int r = 0; r < 4; ++r)
                cp[(size_t)r * ND] = acc[f][g][r] + bv[g];
        }
    }
#undef STAGE
#undef READA
#undef READB
#undef MFMA16
#undef BAR
#undef WAIT_LGKM
#undef HINT_LGKM8
#undef WAIT_VM4
}

// =====================================================================
// Fallback (workspace too small): fp32 inline gather
// =====================================================================
__global__ __launch_bounds__(256) void fallback_gemm(
    const float* __restrict__ x, const float4* __restrict__ cluster4,
    const int* __restrict__ index, const float* __restrict__ bias,
    float* __restrict__ out) {
    const int m = blockIdx.y;
    const int g = blockIdx.x * 256 + threadIdx.x;
    const float* xr = x + (size_t)m * KD;
    float a0 = 0.f, a1 = 0.f, a2 = 0.f, a3 = 0.f;
    for (int k = 0; k < KD; ++k) {
        float xv = xr[k];
        float4 cv = cluster4[index[(size_t)k * 1024 + g]];
        a0 += xv * cv.x; a1 += xv * cv.y; a2 += xv * cv.z; a3 += xv * cv.w;
    }
    size_t o = (size_t)m * ND + (size_t)g * 4;
    out[o + 0] = a0 + bias[g * 4 + 0];
    out[o + 1] = a1 + bias[g * 4 + 1];
    out[o + 2] = a2 + bias[g * 4 + 2];
    out[o + 3] = a3 + bias[g * 4 + 3];
}

extern "C" void kernel_launch(void* const* d_in, const int* in_sizes, int n_in,
                              void* d_out, int out_size, void* d_ws, size_t ws_size,
                              hipStream_t stream) {
    const float* x       = (const float*)d_in[0];
    const float* cluster = (const float*)d_in[1];
    const int*   index   = (const int*)d_in[2];
    const float* bias    = (const float*)d_in[3];
    float* out = (float*)d_out;

    const size_t WT_BYTES = (size_t)ND * KD * sizeof(u16);
    const size_t XB_BYTES = (size_t)MD * KD * sizeof(u16);

    if (ws_size >= WT_BYTES + XB_BYTES) {
        u16* wt = (u16*)d_ws;
        u16* xb = (u16*)((char*)d_ws + WT_BYTES);
        prep<<<2048 + (MD * KD / 8) / 256, 256, 0, stream>>>(
            index, (const float4*)cluster, wt, (const float4*)x, (uint4*)xb);
        gemm256<<<dim3((MD / 256) * (ND / 256)), 512, 0, stream>>>(
            xb, wt, bias, out);
    } else {
        fallback_gemm<<<dim3(1024 / 256, MD), 256, 0, stream>>>(
            x, (const float4*)cluster, index, bias, out);
    }
}